// Round 11
// baseline (116.145 us; speedup 1.0000x reference)
//
#include <hip/hip_runtime.h>

constexpr int E = 8192;
constexpr int N = 4096;
constexpr int CAP = 64;   // max neighbors kept per column (binomial max ~34)

typedef float f4 __attribute__((ext_vector_type(4)));

__device__ __forceinline__ float lrelu(float x) { return x > 0.f ? x : 0.01f * x; }

__device__ __forceinline__ float wave_sum(float v) {
  #pragma unroll
  for (int m = 1; m < 64; m <<= 1) v += __shfl_xor(v, m, 64);
  return v;
}

// Tiny: zero the 2*E contiguous counters (kernel boundary orders this before
// the fused kernel's build atomics).
__global__ __launch_bounds__(256) void zero_k(int* __restrict__ cnt_base)
{
  cnt_base[blockIdx.x * 256 + threadIdx.x] = 0;
}

__device__ __forceinline__ void proc_f4(const f4 v, int flat,
                                        int* __restrict__ cnt, int* __restrict__ idx)
{
  if (v.x != 0.f || v.y != 0.f || v.z != 0.f || v.w != 0.f) {
    const int c = flat & (E - 1);
    const int r = flat >> 13;  // row length 8192
    if (v.x != 0.f) { int s = atomicAdd(&cnt[c    ], 1); if (s < CAP) idx[(c    ) * CAP + s] = r; }
    if (v.y != 0.f) { int s = atomicAdd(&cnt[c + 1], 1); if (s < CAP) idx[(c + 1) * CAP + s] = r; }
    if (v.z != 0.f) { int s = atomicAdd(&cnt[c + 2], 1); if (s < CAP) idx[(c + 2) * CAP + s] = r; }
    if (v.w != 0.f) { int s = atomicAdd(&cnt[c + 3], 1); if (s < CAP) idx[(c + 3) * CAP + s] = r; }
  }
}

// Fused scores + CSC build — scores at the HEAD of the grid (R7 lesson inverted:
// head blocks dispatch first, run their ~5us, and the BW-bound build backfills,
// hiding the score GEMVs instead of serializing them).
// Blocks [0, 2048):         edge scores (4 waves, one edge each)
// Blocks [2048, 3072):      node scores
// Blocks [3072, 3072+1366): e2e stream (268MB, nontemporal — R5 best)
// Blocks [3072+1366, 5120): n2e stream (134MB, cached — R5 best)
__global__ __launch_bounds__(256) void fused_k(
    const f4* __restrict__ e2e, const f4* __restrict__ n2e,
    int* __restrict__ cnt_e, int* __restrict__ idx_e,
    int* __restrict__ cnt_n, int* __restrict__ idx_n,
    const float* __restrict__ ef, const float* __restrict__ We,
    const float* __restrict__ nf, const float* __restrict__ Wn,
    const float* __restrict__ pe, const float* __restrict__ pn,
    float* __restrict__ s_self_e, float* __restrict__ s_nb_e,
    float* __restrict__ s_self_n, float* __restrict__ s_nb_n)
{
  constexpr int n4_e = E * E / 4;
  constexpr int n4_n = N * E / 4;
  constexpr int SCORE_BLKS = E / 4 + N / 4;   // 3072
  constexpr int BLK_E = 1366;                 // of 2048: ~2:1 split (16M:8M f4)

  const int wave = threadIdx.x >> 6, lane = threadIdx.x & 63;

  if (blockIdx.x < E / 4) {
    const int j = blockIdx.x * 4 + wave;
    float emb = 0.f;
    #pragma unroll
    for (int k = 0; k < 32; ++k) emb = fmaf(ef[j * 32 + k], We[k * 64 + lane], emb);
    float a = wave_sum(emb * pe[lane]);
    float b = wave_sum(emb * pe[64 + lane]);
    float c = wave_sum(emb * pn[lane]);
    if (lane == 0) { s_self_e[j] = a; s_nb_e[j] = b; s_self_n[j] = c; }
  } else if (blockIdx.x < SCORE_BLKS) {
    const int n = (blockIdx.x - E / 4) * 4 + wave;
    float emb = 0.f;
    #pragma unroll
    for (int k = 0; k < 64; ++k) emb = fmaf(nf[n * 64 + k], Wn[k * 64 + lane], emb);
    float b = wave_sum(emb * pn[64 + lane]);
    if (lane == 0) s_nb_n[n] = b;
  } else if (blockIdx.x < SCORE_BLKS + BLK_E) {
    const int bid = blockIdx.x - SCORE_BLKS;
    const int stride = BLK_E * 256;
    for (int i = bid * 256 + (int)threadIdx.x; i < n4_e; i += stride) {
      const f4 v = __builtin_nontemporal_load(&e2e[i]);
      proc_f4(v, i << 2, cnt_e, idx_e);
    }
  } else {
    const int bid = blockIdx.x - SCORE_BLKS - BLK_E;
    const int stride = (2048 - BLK_E) * 256;
    for (int i = bid * 256 + (int)threadIdx.x; i < n4_n; i += stride) {
      const f4 v = n2e[i];
      proc_f4(v, i << 2, cnt_n, idx_n);
    }
  }
}

// Wave-parallel phase B: one 64-lane wave per (edge, level) task, no __syncthreads.
// 16384 tasks = 2048 blocks x 8 waves. lvl 1 = edge-level half, lvl 0 = node-level half.
__global__ __launch_bounds__(512) void phase_b_k(
    const int* __restrict__ cnt_e, const int* __restrict__ idx_e,
    const int* __restrict__ cnt_n, const int* __restrict__ idx_n,
    const float* __restrict__ s_self_e, const float* __restrict__ s_nb_e,
    const float* __restrict__ s_self_n, const float* __restrict__ s_nb_n,
    const float* __restrict__ edge_features, const float* __restrict__ node_features,
    const float* __restrict__ W_edge, const float* __restrict__ W_node,
    float* __restrict__ out)
{
  __shared__ float w_sh[8][64];
  __shared__ int   j_sh[8][64];
  __shared__ int   js_sh[8][64];
  __shared__ float mean_sh[8][64];

  const int w    = threadIdx.x >> 6;
  const int lane = threadIdx.x & 63;
  const int gw   = blockIdx.x * 8 + w;
  const int e    = gw >> 1;
  const int lvl  = gw & 1;

  const int   cnt     = lvl ? cnt_e[e] : cnt_n[e];
  const int   deg     = min(cnt, CAP);
  const int*  idx     = lvl ? (idx_e + e * CAP) : (idx_n + e * CAP);
  const float s_self  = lvl ? s_self_e[e] : s_self_n[e];
  const float* s_nb   = lvl ? s_nb_e : s_nb_n;
  const float* feat   = lvl ? edge_features : node_features;
  const int   fdim    = lvl ? 32 : 64;
  const int   total   = lvl ? E : N;
  const float inv_cnt = lvl ? (1.f / E) : (1.f / N);
  const float* W      = lvl ? W_edge : W_node;

  // load neighbor list; rank-sort by index for deterministic fp32 sum order
  int j = 0;
  if (lane < deg) j = idx[lane];
  j_sh[w][lane] = j;
  int rank = 0;
  if (lane < deg)
    for (int t = 0; t < deg; ++t) rank += (j_sh[w][t] < j);
  if (lane < deg) js_sh[w][rank] = j;
  j = js_sh[w][lane];

  // shifted softmax: shift = lrelu(s_self) so each non-neighbor term = exp(0) = 1
  const float shift = lrelu(s_self);
  float wgt = 0.f;
  if (lane < deg) wgt = expf(lrelu(s_self + s_nb[j]) - shift);
  w_sh[w][lane] = wgt;
  const float denom = (float)(total - cnt) + wave_sum(wgt);

  // weighted mean over neighbors for feature f = lane
  float m = 0.f;
  if (lane < fdim) {
    for (int t = 0; t < deg; ++t)
      m = fmaf(w_sh[w][t], feat[js_sh[w][t] * fdim + lane], m);
    m = m / denom * inv_cnt;
  }
  mean_sh[w][lane] = m;

  // epilogue GEMV: out col = lane
  float acc = 0.f;
  for (int f = 0; f < fdim; ++f)
    acc = fmaf(mean_sh[w][f], W[f * 64 + lane], acc);
  out[e * 128 + lvl * 64 + lane] = lrelu(acc);
}

extern "C" void kernel_launch(void* const* d_in, const int* in_sizes, int n_in,
                              void* d_out, int out_size, void* d_ws, size_t ws_size,
                              hipStream_t stream)
{
  const float* node_features = (const float*)d_in[0];
  const float* edge_features = (const float*)d_in[1];
  const float* e2e           = (const float*)d_in[2];  // [E, E] row-major
  const float* n2e           = (const float*)d_in[3];  // [N, E] row-major
  const float* W_node        = (const float*)d_in[4];
  const float* W_edge        = (const float*)d_in[5];
  const float* p_edge        = (const float*)d_in[6];
  const float* p_node        = (const float*)d_in[7];
  float* out = (float*)d_out;

  char* ws = (char*)d_ws;
  int*   cnt_e    = (int*)ws;   ws += (size_t)E * 4;
  int*   cnt_n    = (int*)ws;   ws += (size_t)E * 4;
  int*   idx_e    = (int*)ws;   ws += (size_t)E * CAP * 4;
  int*   idx_n    = (int*)ws;   ws += (size_t)E * CAP * 4;
  float* s_self_e = (float*)ws; ws += (size_t)E * 4;
  float* s_nb_e   = (float*)ws; ws += (size_t)E * 4;
  float* s_self_n = (float*)ws; ws += (size_t)E * 4;
  float* s_nb_n   = (float*)ws; ws += (size_t)N * 4;

  zero_k<<<2 * E / 256, 256, 0, stream>>>(cnt_e /* cnt_e+cnt_n contiguous */);

  fused_k<<<E / 4 + N / 4 + 2048, 256, 0, stream>>>(
      (const f4*)e2e, (const f4*)n2e, cnt_e, idx_e, cnt_n, idx_n,
      edge_features, W_edge, node_features, W_node, p_edge, p_node,
      s_self_e, s_nb_e, s_self_n, s_nb_n);

  phase_b_k<<<E * 2 / 8, 512, 0, stream>>>(cnt_e, idx_e, cnt_n, idx_n,
                                           s_self_e, s_nb_e, s_self_n, s_nb_n,
                                           edge_features, node_features,
                                           W_edge, W_node, out);
}

// Round 12
// 101.745 us; speedup vs baseline: 1.1415x; 1.1415x over previous
//
#include <hip/hip_runtime.h>

constexpr int E = 8192;
constexpr int N = 4096;
constexpr int CAP = 64;   // max neighbors kept per column (binomial max ~34)

typedef float f4 __attribute__((ext_vector_type(4)));

__device__ __forceinline__ float lrelu(float x) { return x > 0.f ? x : 0.01f * x; }

__device__ __forceinline__ float wave_sum(float v) {
  #pragma unroll
  for (int m = 1; m < 64; m <<= 1) v += __shfl_xor(v, m, 64);
  return v;
}

// Fused scores + counter zeroing (R5 structure: must precede build).
__global__ __launch_bounds__(256) void scores_k(
    const float* __restrict__ ef, const float* __restrict__ We,
    const float* __restrict__ nf, const float* __restrict__ Wn,
    const float* __restrict__ pe, const float* __restrict__ pn,
    float* __restrict__ s_self_e, float* __restrict__ s_nb_e,
    float* __restrict__ s_self_n, float* __restrict__ s_nb_n,
    int* __restrict__ cnt_base)
{
  const int gtid = blockIdx.x * 256 + threadIdx.x;
  if (gtid < 2 * E) cnt_base[gtid] = 0;

  const int wave = threadIdx.x >> 6, lane = threadIdx.x & 63;
  if (blockIdx.x < E / 4) {
    const int j = blockIdx.x * 4 + wave;
    float emb = 0.f;
    #pragma unroll
    for (int k = 0; k < 32; ++k) emb = fmaf(ef[j * 32 + k], We[k * 64 + lane], emb);
    float a = wave_sum(emb * pe[lane]);
    float b = wave_sum(emb * pe[64 + lane]);
    float c = wave_sum(emb * pn[lane]);
    if (lane == 0) { s_self_e[j] = a; s_nb_e[j] = b; s_self_n[j] = c; }
  } else {
    const int n = (blockIdx.x - E / 4) * 4 + wave;
    float emb = 0.f;
    #pragma unroll
    for (int k = 0; k < 64; ++k) emb = fmaf(nf[n * 64 + k], Wn[k * 64 + lane], emb);
    float b = wave_sum(emb * pn[64 + lane]);
    if (lane == 0) s_nb_n[n] = b;
  }
}

__device__ __forceinline__ void proc_f4(const f4 v, int flat,
                                        int* __restrict__ cnt, int* __restrict__ idx)
{
  if (v.x != 0.f || v.y != 0.f || v.z != 0.f || v.w != 0.f) {
    const int c = flat & (E - 1);
    const int r = flat >> 13;  // row length 8192
    if (v.x != 0.f) { int s = atomicAdd(&cnt[c    ], 1); if (s < CAP) idx[(c    ) * CAP + s] = r; }
    if (v.y != 0.f) { int s = atomicAdd(&cnt[c + 1], 1); if (s < CAP) idx[(c + 1) * CAP + s] = r; }
    if (v.z != 0.f) { int s = atomicAdd(&cnt[c + 2], 1); if (s < CAP) idx[(c + 2) * CAP + s] = r; }
    if (v.w != 0.f) { int s = atomicAdd(&cnt[c + 3], 1); if (s < CAP) idx[(c + 3) * CAP + s] = r; }
  }
}

// CSC build — CONTIGUOUS PER-BLOCK TILING (the one untested lever):
// 3072 blocks, one contiguous 128KB chunk (8192 f4) each; 32 iterations of
// 4KB per block. Chunks [0,2048) = e2e (nontemporal, R5 best), [2048,3072) =
// n2e (cached, R5 best). vs whole-grid-stride: identical instruction mix /
// cache policy / atomics; ONLY the traffic layout changes (DRAM row locality).
// 2048*8192 = n4_e and 1024*8192 = n4_n exactly -> no guards, no tails.
__global__ __launch_bounds__(256) void build_k(
    const f4* __restrict__ e2e, const f4* __restrict__ n2e,
    int* __restrict__ cnt_e, int* __restrict__ idx_e,
    int* __restrict__ cnt_n, int* __restrict__ idx_n)
{
  constexpr int CHUNK = 8192;  // f4 per block = 128KB

  if (blockIdx.x < 2048) {
    const int base = (int)blockIdx.x * CHUNK + (int)threadIdx.x;
    #pragma unroll 4
    for (int k = 0; k < CHUNK / 256; ++k) {
      const int i = base + k * 256;
      const f4 v = __builtin_nontemporal_load(&e2e[i]);
      proc_f4(v, i << 2, cnt_e, idx_e);
    }
  } else {
    const int base = ((int)blockIdx.x - 2048) * CHUNK + (int)threadIdx.x;
    #pragma unroll 4
    for (int k = 0; k < CHUNK / 256; ++k) {
      const int i = base + k * 256;
      const f4 v = n2e[i];
      proc_f4(v, i << 2, cnt_n, idx_n);
    }
  }
}

// Wave-parallel phase B: one 64-lane wave per (edge, level) task, no __syncthreads.
// 16384 tasks = 2048 blocks x 8 waves. lvl 1 = edge-level half, lvl 0 = node-level half.
__global__ __launch_bounds__(512) void phase_b_k(
    const int* __restrict__ cnt_e, const int* __restrict__ idx_e,
    const int* __restrict__ cnt_n, const int* __restrict__ idx_n,
    const float* __restrict__ s_self_e, const float* __restrict__ s_nb_e,
    const float* __restrict__ s_self_n, const float* __restrict__ s_nb_n,
    const float* __restrict__ edge_features, const float* __restrict__ node_features,
    const float* __restrict__ W_edge, const float* __restrict__ W_node,
    float* __restrict__ out)
{
  __shared__ float w_sh[8][64];
  __shared__ int   j_sh[8][64];
  __shared__ int   js_sh[8][64];
  __shared__ float mean_sh[8][64];

  const int w    = threadIdx.x >> 6;
  const int lane = threadIdx.x & 63;
  const int gw   = blockIdx.x * 8 + w;
  const int e    = gw >> 1;
  const int lvl  = gw & 1;

  const int   cnt     = lvl ? cnt_e[e] : cnt_n[e];
  const int   deg     = min(cnt, CAP);
  const int*  idx     = lvl ? (idx_e + e * CAP) : (idx_n + e * CAP);
  const float s_self  = lvl ? s_self_e[e] : s_self_n[e];
  const float* s_nb   = lvl ? s_nb_e : s_nb_n;
  const float* feat   = lvl ? edge_features : node_features;
  const int   fdim    = lvl ? 32 : 64;
  const int   total   = lvl ? E : N;
  const float inv_cnt = lvl ? (1.f / E) : (1.f / N);
  const float* W      = lvl ? W_edge : W_node;

  // load neighbor list; rank-sort by index for deterministic fp32 sum order
  int j = 0;
  if (lane < deg) j = idx[lane];
  j_sh[w][lane] = j;
  int rank = 0;
  if (lane < deg)
    for (int t = 0; t < deg; ++t) rank += (j_sh[w][t] < j);
  if (lane < deg) js_sh[w][rank] = j;
  j = js_sh[w][lane];

  // shifted softmax: shift = lrelu(s_self) so each non-neighbor term = exp(0) = 1
  const float shift = lrelu(s_self);
  float wgt = 0.f;
  if (lane < deg) wgt = expf(lrelu(s_self + s_nb[j]) - shift);
  w_sh[w][lane] = wgt;
  const float denom = (float)(total - cnt) + wave_sum(wgt);

  // weighted mean over neighbors for feature f = lane
  float m = 0.f;
  if (lane < fdim) {
    for (int t = 0; t < deg; ++t)
      m = fmaf(w_sh[w][t], feat[js_sh[w][t] * fdim + lane], m);
    m = m / denom * inv_cnt;
  }
  mean_sh[w][lane] = m;

  // epilogue GEMV: out col = lane
  float acc = 0.f;
  for (int f = 0; f < fdim; ++f)
    acc = fmaf(mean_sh[w][f], W[f * 64 + lane], acc);
  out[e * 128 + lvl * 64 + lane] = lrelu(acc);
}

extern "C" void kernel_launch(void* const* d_in, const int* in_sizes, int n_in,
                              void* d_out, int out_size, void* d_ws, size_t ws_size,
                              hipStream_t stream)
{
  const float* node_features = (const float*)d_in[0];
  const float* edge_features = (const float*)d_in[1];
  const float* e2e           = (const float*)d_in[2];  // [E, E] row-major
  const float* n2e           = (const float*)d_in[3];  // [N, E] row-major
  const float* W_node        = (const float*)d_in[4];
  const float* W_edge        = (const float*)d_in[5];
  const float* p_edge        = (const float*)d_in[6];
  const float* p_node        = (const float*)d_in[7];
  float* out = (float*)d_out;

  char* ws = (char*)d_ws;
  int*   cnt_e    = (int*)ws;   ws += (size_t)E * 4;
  int*   cnt_n    = (int*)ws;   ws += (size_t)E * 4;
  int*   idx_e    = (int*)ws;   ws += (size_t)E * CAP * 4;
  int*   idx_n    = (int*)ws;   ws += (size_t)E * CAP * 4;
  float* s_self_e = (float*)ws; ws += (size_t)E * 4;
  float* s_nb_e   = (float*)ws; ws += (size_t)E * 4;
  float* s_self_n = (float*)ws; ws += (size_t)E * 4;
  float* s_nb_n   = (float*)ws; ws += (size_t)N * 4;

  scores_k<<<E / 4 + N / 4, 256, 0, stream>>>(
      edge_features, W_edge, node_features, W_node, p_edge, p_node,
      s_self_e, s_nb_e, s_self_n, s_nb_n, cnt_e /* cnt_e+cnt_n contiguous */);

  build_k<<<3072, 256, 0, stream>>>((const f4*)e2e, (const f4*)n2e,
                                    cnt_e, idx_e, cnt_n, idx_n);

  phase_b_k<<<E * 2 / 8, 512, 0, stream>>>(cnt_e, idx_e, cnt_n, idx_n,
                                           s_self_e, s_nb_e, s_self_n, s_nb_n,
                                           edge_features, node_features,
                                           W_edge, W_node, out);
}

// Round 13
// 95.946 us; speedup vs baseline: 1.2105x; 1.0604x over previous
//
#include <hip/hip_runtime.h>

constexpr int E = 8192;
constexpr int N = 4096;
constexpr int CAP = 64;   // max neighbors kept per column (binomial max ~34)

typedef float f4 __attribute__((ext_vector_type(4)));

__device__ __forceinline__ float lrelu(float x) { return x > 0.f ? x : 0.01f * x; }

__device__ __forceinline__ float wave_sum(float v) {
  #pragma unroll
  for (int m = 1; m < 64; m <<= 1) v += __shfl_xor(v, m, 64);
  return v;
}

// Fused scores + counter zeroing (R5 structure: must precede build).
// Feature-row loads are COALESCED (lane k holds element k) then broadcast via
// __shfl (2-cyc VALU) instead of per-k same-address loads (~50cyc L1 trips on
// the FMA critical chain).
__global__ __launch_bounds__(256) void scores_k(
    const float* __restrict__ ef, const float* __restrict__ We,
    const float* __restrict__ nf, const float* __restrict__ Wn,
    const float* __restrict__ pe, const float* __restrict__ pn,
    float* __restrict__ s_self_e, float* __restrict__ s_nb_e,
    float* __restrict__ s_self_n, float* __restrict__ s_nb_n,
    int* __restrict__ cnt_base)
{
  const int gtid = blockIdx.x * 256 + threadIdx.x;
  if (gtid < 2 * E) cnt_base[gtid] = 0;

  const int wave = threadIdx.x >> 6, lane = threadIdx.x & 63;
  if (blockIdx.x < E / 4) {
    const int j = blockIdx.x * 4 + wave;
    const float r = ef[j * 32 + (lane & 31)];   // coalesced row load
    float emb = 0.f;
    #pragma unroll
    for (int k = 0; k < 32; ++k)
      emb = fmaf(__shfl(r, k, 64), We[k * 64 + lane], emb);
    float a = wave_sum(emb * pe[lane]);
    float b = wave_sum(emb * pe[64 + lane]);
    float c = wave_sum(emb * pn[lane]);
    if (lane == 0) { s_self_e[j] = a; s_nb_e[j] = b; s_self_n[j] = c; }
  } else {
    const int n = (blockIdx.x - E / 4) * 4 + wave;
    const float r = nf[n * 64 + lane];          // coalesced row load
    float emb = 0.f;
    #pragma unroll
    for (int k = 0; k < 64; ++k)
      emb = fmaf(__shfl(r, k, 64), Wn[k * 64 + lane], emb);
    float b = wave_sum(emb * pn[64 + lane]);
    if (lane == 0) s_nb_n[n] = b;
  }
}

__device__ __forceinline__ void proc_f4(const f4 v, int flat,
                                        int* __restrict__ cnt, int* __restrict__ idx)
{
  if (v.x != 0.f || v.y != 0.f || v.z != 0.f || v.w != 0.f) {
    const int c = flat & (E - 1);
    const int r = flat >> 13;  // row length 8192
    if (v.x != 0.f) { int s = atomicAdd(&cnt[c    ], 1); if (s < CAP) idx[(c    ) * CAP + s] = r; }
    if (v.y != 0.f) { int s = atomicAdd(&cnt[c + 1], 1); if (s < CAP) idx[(c + 1) * CAP + s] = r; }
    if (v.z != 0.f) { int s = atomicAdd(&cnt[c + 2], 1); if (s < CAP) idx[(c + 2) * CAP + s] = r; }
    if (v.w != 0.f) { int s = atomicAdd(&cnt[c + 3], 1); if (s < CAP) idx[(c + 3) * CAP + s] = r; }
  }
}

// CSC build — R5's exact best config: whole-grid-stride (R12 showed it beats
// contiguous tiling), e2e nontemporal (no L3 allocation -> n2e stays resident),
// n2e cached (L3-hit across replays), 2:1 block split.
__global__ __launch_bounds__(256) void build_k(
    const f4* __restrict__ e2e, const f4* __restrict__ n2e,
    int* __restrict__ cnt_e, int* __restrict__ idx_e,
    int* __restrict__ cnt_n, int* __restrict__ idx_n)
{
  constexpr int n4_e = E * E / 4;
  constexpr int n4_n = N * E / 4;
  constexpr int BLK_E = 1366;  // of 2048: ~2:1 split matching 16M:8M f4 elements

  if (blockIdx.x < BLK_E) {
    const int stride = BLK_E * 256;
    for (int i = (int)blockIdx.x * 256 + (int)threadIdx.x; i < n4_e; i += stride) {
      const f4 v = __builtin_nontemporal_load(&e2e[i]);
      proc_f4(v, i << 2, cnt_e, idx_e);
    }
  } else {
    const int stride = (2048 - BLK_E) * 256;
    for (int i = ((int)blockIdx.x - BLK_E) * 256 + (int)threadIdx.x; i < n4_n; i += stride) {
      const f4 v = n2e[i];
      proc_f4(v, i << 2, cnt_n, idx_n);
    }
  }
}

// Wave-parallel phase B: one 64-lane wave per (edge, level) task, no __syncthreads.
// 16384 tasks = 2048 blocks x 8 waves. lvl 1 = edge-level half, lvl 0 = node-level half.
__global__ __launch_bounds__(512) void phase_b_k(
    const int* __restrict__ cnt_e, const int* __restrict__ idx_e,
    const int* __restrict__ cnt_n, const int* __restrict__ idx_n,
    const float* __restrict__ s_self_e, const float* __restrict__ s_nb_e,
    const float* __restrict__ s_self_n, const float* __restrict__ s_nb_n,
    const float* __restrict__ edge_features, const float* __restrict__ node_features,
    const float* __restrict__ W_edge, const float* __restrict__ W_node,
    float* __restrict__ out)
{
  __shared__ float w_sh[8][64];
  __shared__ int   j_sh[8][64];
  __shared__ int   js_sh[8][64];
  __shared__ float mean_sh[8][64];

  const int w    = threadIdx.x >> 6;
  const int lane = threadIdx.x & 63;
  const int gw   = blockIdx.x * 8 + w;
  const int e    = gw >> 1;
  const int lvl  = gw & 1;

  const int   cnt     = lvl ? cnt_e[e] : cnt_n[e];
  const int   deg     = min(cnt, CAP);
  const int*  idx     = lvl ? (idx_e + e * CAP) : (idx_n + e * CAP);
  const float s_self  = lvl ? s_self_e[e] : s_self_n[e];
  const float* s_nb   = lvl ? s_nb_e : s_nb_n;
  const float* feat   = lvl ? edge_features : node_features;
  const int   fdim    = lvl ? 32 : 64;
  const int   total   = lvl ? E : N;
  const float inv_cnt = lvl ? (1.f / E) : (1.f / N);
  const float* W      = lvl ? W_edge : W_node;

  // load neighbor list; rank-sort by index for deterministic fp32 sum order
  int j = 0;
  if (lane < deg) j = idx[lane];
  j_sh[w][lane] = j;
  int rank = 0;
  if (lane < deg)
    for (int t = 0; t < deg; ++t) rank += (j_sh[w][t] < j);
  if (lane < deg) js_sh[w][rank] = j;
  j = js_sh[w][lane];

  // shifted softmax: shift = lrelu(s_self) so each non-neighbor term = exp(0) = 1
  const float shift = lrelu(s_self);
  float wgt = 0.f;
  if (lane < deg) wgt = expf(lrelu(s_self + s_nb[j]) - shift);
  w_sh[w][lane] = wgt;
  const float denom = (float)(total - cnt) + wave_sum(wgt);

  // weighted mean over neighbors for feature f = lane
  float m = 0.f;
  if (lane < fdim) {
    for (int t = 0; t < deg; ++t)
      m = fmaf(w_sh[w][t], feat[js_sh[w][t] * fdim + lane], m);
    m = m / denom * inv_cnt;
  }
  mean_sh[w][lane] = m;

  // epilogue GEMV: out col = lane
  float acc = 0.f;
  for (int f = 0; f < fdim; ++f)
    acc = fmaf(mean_sh[w][f], W[f * 64 + lane], acc);
  out[e * 128 + lvl * 64 + lane] = lrelu(acc);
}

extern "C" void kernel_launch(void* const* d_in, const int* in_sizes, int n_in,
                              void* d_out, int out_size, void* d_ws, size_t ws_size,
                              hipStream_t stream)
{
  const float* node_features = (const float*)d_in[0];
  const float* edge_features = (const float*)d_in[1];
  const float* e2e           = (const float*)d_in[2];  // [E, E] row-major
  const float* n2e           = (const float*)d_in[3];  // [N, E] row-major
  const float* W_node        = (const float*)d_in[4];
  const float* W_edge        = (const float*)d_in[5];
  const float* p_edge        = (const float*)d_in[6];
  const float* p_node        = (const float*)d_in[7];
  float* out = (float*)d_out;

  char* ws = (char*)d_ws;
  int*   cnt_e    = (int*)ws;   ws += (size_t)E * 4;
  int*   cnt_n    = (int*)ws;   ws += (size_t)E * 4;
  int*   idx_e    = (int*)ws;   ws += (size_t)E * CAP * 4;
  int*   idx_n    = (int*)ws;   ws += (size_t)E * CAP * 4;
  float* s_self_e = (float*)ws; ws += (size_t)E * 4;
  float* s_nb_e   = (float*)ws; ws += (size_t)E * 4;
  float* s_self_n = (float*)ws; ws += (size_t)E * 4;
  float* s_nb_n   = (float*)ws; ws += (size_t)N * 4;

  scores_k<<<E / 4 + N / 4, 256, 0, stream>>>(
      edge_features, W_edge, node_features, W_node, p_edge, p_node,
      s_self_e, s_nb_e, s_self_n, s_nb_n, cnt_e /* cnt_e+cnt_n contiguous */);

  build_k<<<2048, 256, 0, stream>>>((const f4*)e2e, (const f4*)n2e,
                                    cnt_e, idx_e, cnt_n, idx_n);

  phase_b_k<<<E * 2 / 8, 512, 0, stream>>>(cnt_e, idx_e, cnt_n, idx_n,
                                           s_self_e, s_nb_e, s_self_n, s_nb_n,
                                           edge_features, node_features,
                                           W_edge, W_node, out);
}